// Round 1
// baseline (774.445 us; speedup 1.0000x reference)
//
#include <hip/hip_runtime.h>
#include <stdint.h>

#define HW 65536

typedef __attribute__((ext_vector_type(8))) short short8;
typedef __attribute__((ext_vector_type(4))) float f32x4;
typedef unsigned short u16;

struct __align__(8) us4 { u16 x, y, z, w; };

__device__ __forceinline__ u16 f2bf(float f) {
  union { float f; uint32_t u; } v; v.f = f;
  uint32_t r = v.u + 0x7FFFu + ((v.u >> 16) & 1u);   // round-to-nearest-even
  return (u16)(r >> 16);
}

__device__ __forceinline__ us4 pack4(float a, float b, float c, float d) {
  us4 o; o.x = f2bf(a); o.y = f2bf(b); o.z = f2bf(c); o.w = f2bf(d); return o;
}

// Reorder OIHW fp32 weights -> bf16 [co][tap*Cp + ci], zero-padded in ci (and co).
__global__ void reorder_w_k(const float* __restrict__ src, u16* __restrict__ dst,
                            int CO, int CI, int COp, int Cp) {
  int idx = blockIdx.x * 256 + threadIdx.x;
  int tot = COp * 9 * Cp;
  if (idx >= tot) return;
  int co = idx / (9 * Cp);
  int r = idx - co * (9 * Cp);
  int tap = r / Cp;
  int ci = r - tap * Cp;
  float v = 0.f;
  if (co < CO && ci < CI) v = src[(co * CI + ci) * 9 + tap];
  dst[idx] = f2bf(v);
}

// Build fusion_in: NHWC bf16, 32 ch (24 valid): [|ll1-ll0| x16, gamma_up x4, sigma_ll1 x4, 0 x8]
__global__ void fusion_in_k(const float* __restrict__ ft0, const float* __restrict__ ft1,
                            const float* __restrict__ gup, const float* __restrict__ ca,
                            const float* __restrict__ cb, u16* __restrict__ fin) {
  const int p = blockIdx.x * 256 + threadIdx.x;   // 0..262143
  const int n = p >> 16;
  const int pp = p & 65535;
  const float* b0 = ft0 + (size_t)n * 64 * HW + pp;
  const float* b1 = ft1 + (size_t)n * 64 * HW + pp;
  const float a = ca[0], bb = cb[0];
  u16* row = fin + (size_t)p * 32;
#pragma unroll
  for (int c4 = 0; c4 < 16; c4 += 4)
    *(us4*)(row + c4) = pack4(fabsf(b1[(c4 + 0) * HW] - b0[(c4 + 0) * HW]),
                              fabsf(b1[(c4 + 1) * HW] - b0[(c4 + 1) * HW]),
                              fabsf(b1[(c4 + 2) * HW] - b0[(c4 + 2) * HW]),
                              fabsf(b1[(c4 + 3) * HW] - b0[(c4 + 3) * HW]));
  const float* gu = gup + (size_t)n * 4 * HW + pp;
  *(us4*)(row + 16) = pack4(gu[0], gu[HW], gu[2 * HW], gu[3 * HW]);
  *(us4*)(row + 20) = pack4(fminf(fmaxf(b1[0 * HW], 0.f), 1.f) * a + bb,
                            fminf(fmaxf(b1[1 * HW], 0.f), 1.f) * a + bb,
                            fminf(fmaxf(b1[2 * HW], 0.f), 1.f) * a + bb,
                            fminf(fmaxf(b1[3 * HW], 0.f), 1.f) * a + bb);
  const us4 zz = {0, 0, 0, 0};
  *(us4*)(row + 24) = zz;
  *(us4*)(row + 28) = zz;
}

// After gamma: fusion_out (fp32 NCHW to d_out), sigma (fp32 NCHW to d_out),
// and denoise_in NHWC bf16 128ch (100 valid): [fusion_out x64, ll1 x16, dd x16, sigma x4, 0 x28]
__global__ void fusion_post_k(const float* __restrict__ ft0, const float* __restrict__ ft1,
                              const float* __restrict__ dd, const float* __restrict__ ca,
                              const float* __restrict__ cb, const float* __restrict__ gamma,
                              float* __restrict__ fo_out, float* __restrict__ si_out,
                              u16* __restrict__ din) {
  const int p = blockIdx.x * 256 + threadIdx.x;
  const int n = p >> 16;
  const int pp = p & 65535;
  const float* b0 = ft0 + (size_t)n * 64 * HW + pp;
  const float* b1 = ft1 + (size_t)n * 64 * HW + pp;
  float* fo = fo_out + (size_t)n * 64 * HW + pp;
  const float a = ca[0], bb = cb[0];
  float g[4];
#pragma unroll
  for (int j = 0; j < 4; ++j) g[j] = gamma[((size_t)n * 4 + j) * HW + pp];
  u16* drow = din + (size_t)p * 128;
#pragma unroll
  for (int c4 = 0; c4 < 64; c4 += 4) {
    const float gg = g[c4 >> 4];
    float v[4];
#pragma unroll
    for (int r = 0; r < 4; ++r) {
      const float f0 = b0[(c4 + r) * HW];
      const float f1 = b1[(c4 + r) * HW];
      const float x = f0 + gg * (f1 - f0);
      fo[(c4 + r) * HW] = x;
      v[r] = x;
    }
    *(us4*)(drow + c4) = pack4(v[0], v[1], v[2], v[3]);
  }
#pragma unroll
  for (int c4 = 0; c4 < 16; c4 += 4)
    *(us4*)(drow + 64 + c4) = pack4(b1[(c4 + 0) * HW], b1[(c4 + 1) * HW],
                                    b1[(c4 + 2) * HW], b1[(c4 + 3) * HW]);
  const float* dn = dd + (size_t)n * 16 * HW + pp;
#pragma unroll
  for (int c4 = 0; c4 < 16; c4 += 4)
    *(us4*)(drow + 80 + c4) = pack4(dn[(c4 + 0) * HW], dn[(c4 + 1) * HW],
                                    dn[(c4 + 2) * HW], dn[(c4 + 3) * HW]);
  float s[4];
#pragma unroll
  for (int j = 0; j < 4; ++j) {
    const float f0 = b0[j * HW], f1 = b1[j * HW];
    const float sl0 = fminf(fmaxf(f0, 0.f), 1.f) * a + bb;
    const float sl1 = fminf(fmaxf(f1, 0.f), 1.f) * a + bb;
    const float om = 1.f - g[j];
    s[j] = om * om * sl0 + g[j] * g[j] * sl1;
    si_out[((size_t)n * 4 + j) * HW + pp] = s[j];
  }
  *(us4*)(drow + 96) = pack4(s[0], s[1], s[2], s[3]);
  const us4 zz = {0, 0, 0, 0};
#pragma unroll
  for (int c4 = 100; c4 < 128; c4 += 4) *(us4*)(drow + c4) = zz;
}

// Implicit-GEMM 3x3 conv, pad=1. Input NHWC bf16 (CIN = mult of 32). One block per
// output row (n,y): M = MT*16 out-channels x N = 256 pixels. K-chunk = one tap x 32 ci.
// OMODE 0: bf16 NHWC out (64ch) + bias + relu
// OMODE 1: fp32 NCHW out (64ch) + bias            (denoise_out)
// OMODE 2: fp32 NCHW out (4ch)  + bias + sigmoid  (gamma, MT=1)
template <int CIN, int MT, int OMODE>
__global__ __launch_bounds__(256, 2) void conv3_k(
    const u16* __restrict__ in, const u16* __restrict__ wr,
    const float* __restrict__ bias, u16* __restrict__ obf,
    float* __restrict__ of32) {
  constexpr int M = MT * 16;
  constexpr int CHPT = CIN / 32;
  constexpr int KCH = 9 * CHPT;
  __shared__ __align__(16) u16 Alds[4 * M * 8];     // [g][co][8]
  __shared__ __align__(16) u16 Blds[4 * 256 * 8];   // [g][pix][8]
  const int tid = threadIdx.x;
  const int w = tid >> 6;
  const int lane = tid & 63;
  const int l15 = lane & 15;
  const int quad = lane >> 4;
  const int n = blockIdx.x >> 8;
  const int y = blockIdx.x & 255;

  f32x4 acc[MT][4];
#pragma unroll
  for (int mt = 0; mt < MT; ++mt)
#pragma unroll
    for (int nt = 0; nt < 4; ++nt) acc[mt][nt] = (f32x4){0.f, 0.f, 0.f, 0.f};

  const u16* inb = in + (size_t)n * HW * CIN;

  for (int kc = 0; kc < KCH; ++kc) {
    const int tap = kc / CHPT;
    const int ci0 = (kc - tap * CHPT) * 32;
    const int ky = tap / 3;
    const int kx = tap - ky * 3;
    __syncthreads();
    // stage A (weights): dense lane-contiguous 16B writes per region
    if (tid < M * 4) {
      const int co = tid % M;
      const int g = tid / M;
      const float4* s = (const float4*)(wr + (size_t)co * (9 * CIN) + tap * CIN + ci0 + g * 8);
      *(float4*)&Alds[(g * M + co) * 8] = *s;
    }
    // stage B (im2col row): thread = pixel, 4 k-groups of 8ch
    {
      const int y2 = y + ky - 1;
      const int x2 = tid + kx - 1;
      const bool val = (y2 >= 0) && (y2 < 256) && (x2 >= 0) && (x2 < 256);
      const float4* s = (const float4*)(inb + (y2 * 256 + x2) * CIN + ci0);
      const float4 z = {0.f, 0.f, 0.f, 0.f};
#pragma unroll
      for (int g = 0; g < 4; ++g) {
        float4 v = z;
        if (val) v = s[g];
        *(float4*)&Blds[(g * 256 + tid) * 8] = v;
      }
    }
    __syncthreads();
    short8 a[MT], b[4];
#pragma unroll
    for (int mt = 0; mt < MT; ++mt)
      a[mt] = *(const short8*)&Alds[(quad * M + mt * 16 + l15) * 8];
#pragma unroll
    for (int nt = 0; nt < 4; ++nt)
      b[nt] = *(const short8*)&Blds[(quad * 256 + (w * 4 + nt) * 16 + l15) * 8];
#pragma unroll
    for (int mt = 0; mt < MT; ++mt)
#pragma unroll
      for (int nt = 0; nt < 4; ++nt)
        acc[mt][nt] = __builtin_amdgcn_mfma_f32_16x16x32_bf16(a[mt], b[nt], acc[mt][nt], 0, 0, 0);
  }

  // Epilogue. C/D layout: col(pix)=lane&15, row(co within 16-tile)=quad*4+reg
  if (OMODE == 0) {
    u16* ob = obf + ((size_t)n * 256 + y) * 256 * 64;
#pragma unroll
    for (int mt = 0; mt < MT; ++mt) {
      const int co = mt * 16 + quad * 4;
      const float b0 = bias[co], b1 = bias[co + 1], b2 = bias[co + 2], b3 = bias[co + 3];
#pragma unroll
      for (int nt = 0; nt < 4; ++nt) {
        const int pix = (w * 4 + nt) * 16 + l15;
        f32x4 c = acc[mt][nt];
        us4 o = pack4(fmaxf(c[0] + b0, 0.f), fmaxf(c[1] + b1, 0.f),
                      fmaxf(c[2] + b2, 0.f), fmaxf(c[3] + b3, 0.f));
        *(us4*)(ob + (size_t)pix * 64 + co) = o;
      }
    }
  } else if (OMODE == 1) {
#pragma unroll
    for (int mt = 0; mt < MT; ++mt) {
#pragma unroll
      for (int nt = 0; nt < 4; ++nt) {
        const int pix = (w * 4 + nt) * 16 + l15;
        f32x4 c = acc[mt][nt];
#pragma unroll
        for (int r = 0; r < 4; ++r) {
          const int co = mt * 16 + quad * 4 + r;
          of32[((size_t)n * 64 + co) * HW + y * 256 + pix] = c[r] + bias[co];
        }
      }
    }
  } else {
    if (quad == 0) {
#pragma unroll
      for (int nt = 0; nt < 4; ++nt) {
        const int pix = (w * 4 + nt) * 16 + l15;
        f32x4 c = acc[0][nt];
#pragma unroll
        for (int r = 0; r < 4; ++r) {
          const float v = c[r] + bias[r];
          of32[((size_t)n * 4 + r) * HW + y * 256 + pix] = 1.f / (1.f + expf(-v));
        }
      }
    }
  }
}

extern "C" void kernel_launch(void* const* d_in, const int* in_sizes, int n_in,
                              void* d_out, int out_size, void* d_ws, size_t ws_size,
                              hipStream_t stream) {
  (void)in_sizes; (void)n_in; (void)out_size; (void)ws_size;
  const float* ft0 = (const float*)d_in[0];
  const float* ft1 = (const float*)d_in[1];
  const float* gup = (const float*)d_in[2];
  const float* dd  = (const float*)d_in[3];
  const float* ca  = (const float*)d_in[4];
  const float* cb  = (const float*)d_in[5];
  const float* fw1 = (const float*)d_in[6];  const float* fb1 = (const float*)d_in[7];
  const float* fw2 = (const float*)d_in[8];  const float* fb2 = (const float*)d_in[9];
  const float* fw3 = (const float*)d_in[10]; const float* fb3 = (const float*)d_in[11];
  const float* dw1 = (const float*)d_in[12]; const float* db1 = (const float*)d_in[13];
  const float* dw2 = (const float*)d_in[14]; const float* db2 = (const float*)d_in[15];
  const float* dw3 = (const float*)d_in[16]; const float* db3 = (const float*)d_in[17];

  float* out = (float*)d_out;
  float* fo_out = out;                               // fusion_out  4*64*HW
  float* do_out = out + (size_t)4 * 64 * HW;         // denoise_out 4*64*HW
  float* ga_out = out + (size_t)8 * 64 * HW;         // gamma       4*4*HW
  float* si_out = ga_out + (size_t)4 * 4 * HW;       // sigma       4*4*HW

  char* ws = (char*)d_ws;
  u16* WR1 = (u16*)(ws);
  u16* WR2 = (u16*)(ws + 36864);
  u16* WR3 = (u16*)(ws + 110592);
  u16* WD1 = (u16*)(ws + 129024);
  u16* WD2 = (u16*)(ws + 276480);
  u16* WD3 = (u16*)(ws + 350208);
  u16* FIN = (u16*)(ws + (1 << 20));                 // 4*HW*32  bf16 = 16 MB
  u16* H1  = (u16*)(ws + 17825792);                  // 4*HW*64  bf16 = 32 MB
  u16* H2  = (u16*)(ws + 51380224);                  // 4*HW*64  bf16 = 32 MB
  // denoise_in (4*HW*128 bf16 = 64 MB) overlaps denoise_out region: dead before dconv3 writes it
  u16* DIN = (u16*)do_out;

  dim3 blk(256);
  reorder_w_k<<<(64 * 9 * 32 + 255) / 256, blk, 0, stream>>>(fw1, WR1, 64, 24, 64, 32);
  reorder_w_k<<<(64 * 9 * 64 + 255) / 256, blk, 0, stream>>>(fw2, WR2, 64, 64, 64, 64);
  reorder_w_k<<<(16 * 9 * 64 + 255) / 256, blk, 0, stream>>>(fw3, WR3, 4, 64, 16, 64);
  reorder_w_k<<<(64 * 9 * 128 + 255) / 256, blk, 0, stream>>>(dw1, WD1, 64, 100, 64, 128);
  reorder_w_k<<<(64 * 9 * 64 + 255) / 256, blk, 0, stream>>>(dw2, WD2, 64, 64, 64, 64);
  reorder_w_k<<<(64 * 9 * 64 + 255) / 256, blk, 0, stream>>>(dw3, WD3, 64, 64, 64, 64);

  fusion_in_k<<<1024, blk, 0, stream>>>(ft0, ft1, gup, ca, cb, FIN);
  conv3_k<32, 4, 0><<<1024, blk, 0, stream>>>(FIN, WR1, fb1, H1, nullptr);
  conv3_k<64, 4, 0><<<1024, blk, 0, stream>>>(H1, WR2, fb2, H2, nullptr);
  conv3_k<64, 1, 2><<<1024, blk, 0, stream>>>(H2, WR3, fb3, nullptr, ga_out);
  fusion_post_k<<<1024, blk, 0, stream>>>(ft0, ft1, dd, ca, cb, ga_out, fo_out, si_out, DIN);
  conv3_k<128, 4, 0><<<1024, blk, 0, stream>>>(DIN, WD1, db1, H1, nullptr);
  conv3_k<64, 4, 0><<<1024, blk, 0, stream>>>(H1, WD2, db2, H2, nullptr);
  conv3_k<64, 4, 1><<<1024, blk, 0, stream>>>(H2, WD3, db3, nullptr, do_out);
}

// Round 2
// 693.276 us; speedup vs baseline: 1.1171x; 1.1171x over previous
//
#include <hip/hip_runtime.h>
#include <stdint.h>

#define HW 65536

typedef __attribute__((ext_vector_type(8))) short short8;
typedef __attribute__((ext_vector_type(4))) float f32x4;
typedef unsigned short u16;

struct __align__(8) us4 { u16 x, y, z, w; };

__device__ __forceinline__ u16 f2bf(float f) {
  union { float f; uint32_t u; } v; v.f = f;
  uint32_t r = v.u + 0x7FFFu + ((v.u >> 16) & 1u);   // round-to-nearest-even
  return (u16)(r >> 16);
}

__device__ __forceinline__ us4 pack4(float a, float b, float c, float d) {
  us4 o; o.x = f2bf(a); o.y = f2bf(b); o.z = f2bf(c); o.w = f2bf(d); return o;
}

// Reorder OIHW fp32 weights -> bf16 [tap][cigroup][co][8], zero-padded in ci and co.
// dst idx = ((tap*(Cp/8) + cg)*COp + co)*8 + cc ; ci = cg*8+cc
__global__ void reorder_w_k(const float* __restrict__ src, u16* __restrict__ dst,
                            int CO, int CI, int COp, int Cp) {
  int idx = blockIdx.x * 256 + threadIdx.x;
  int tot = COp * 9 * Cp;
  if (idx >= tot) return;
  int cc = idx & 7;
  int t = idx >> 3;
  int co = t % COp;
  int u = t / COp;
  int cgn = Cp >> 3;
  int cg = u % cgn;
  int tap = u / cgn;
  int ci = cg * 8 + cc;
  float v = 0.f;
  if (co < CO && ci < CI) v = src[(co * CI + ci) * 9 + tap];
  dst[idx] = f2bf(v);
}

// Build fusion_in: NHWC bf16, 32 ch (24 valid): [|ll1-ll0| x16, gamma_up x4, sigma_ll1 x4, 0 x8]
__global__ void fusion_in_k(const float* __restrict__ ft0, const float* __restrict__ ft1,
                            const float* __restrict__ gup, const float* __restrict__ ca,
                            const float* __restrict__ cb, u16* __restrict__ fin) {
  const int p = blockIdx.x * 256 + threadIdx.x;   // 0..262143
  const int n = p >> 16;
  const int pp = p & 65535;
  const float* b0 = ft0 + (size_t)n * 64 * HW + pp;
  const float* b1 = ft1 + (size_t)n * 64 * HW + pp;
  const float a = ca[0], bb = cb[0];
  u16* row = fin + (size_t)p * 32;
#pragma unroll
  for (int c4 = 0; c4 < 16; c4 += 4)
    *(us4*)(row + c4) = pack4(fabsf(b1[(c4 + 0) * HW] - b0[(c4 + 0) * HW]),
                              fabsf(b1[(c4 + 1) * HW] - b0[(c4 + 1) * HW]),
                              fabsf(b1[(c4 + 2) * HW] - b0[(c4 + 2) * HW]),
                              fabsf(b1[(c4 + 3) * HW] - b0[(c4 + 3) * HW]));
  const float* gu = gup + (size_t)n * 4 * HW + pp;
  *(us4*)(row + 16) = pack4(gu[0], gu[HW], gu[2 * HW], gu[3 * HW]);
  *(us4*)(row + 20) = pack4(fminf(fmaxf(b1[0 * HW], 0.f), 1.f) * a + bb,
                            fminf(fmaxf(b1[1 * HW], 0.f), 1.f) * a + bb,
                            fminf(fmaxf(b1[2 * HW], 0.f), 1.f) * a + bb,
                            fminf(fmaxf(b1[3 * HW], 0.f), 1.f) * a + bb);
  const us4 zz = {0, 0, 0, 0};
  *(us4*)(row + 24) = zz;
  *(us4*)(row + 28) = zz;
}

// After gamma: fusion_out (fp32 NCHW to d_out), sigma (fp32 NCHW to d_out),
// and denoise_in NHWC bf16 128ch (100 valid): [fusion_out x64, ll1 x16, dd x16, sigma x4, 0 x28]
__global__ void fusion_post_k(const float* __restrict__ ft0, const float* __restrict__ ft1,
                              const float* __restrict__ dd, const float* __restrict__ ca,
                              const float* __restrict__ cb, const float* __restrict__ gamma,
                              float* __restrict__ fo_out, float* __restrict__ si_out,
                              u16* __restrict__ din) {
  const int p = blockIdx.x * 256 + threadIdx.x;
  const int n = p >> 16;
  const int pp = p & 65535;
  const float* b0 = ft0 + (size_t)n * 64 * HW + pp;
  const float* b1 = ft1 + (size_t)n * 64 * HW + pp;
  float* fo = fo_out + (size_t)n * 64 * HW + pp;
  const float a = ca[0], bb = cb[0];
  float g[4];
#pragma unroll
  for (int j = 0; j < 4; ++j) g[j] = gamma[((size_t)n * 4 + j) * HW + pp];
  u16* drow = din + (size_t)p * 128;
#pragma unroll
  for (int c4 = 0; c4 < 64; c4 += 4) {
    const float gg = g[c4 >> 4];
    float v[4];
#pragma unroll
    for (int r = 0; r < 4; ++r) {
      const float f0 = b0[(c4 + r) * HW];
      const float f1 = b1[(c4 + r) * HW];
      const float x = f0 + gg * (f1 - f0);
      fo[(c4 + r) * HW] = x;
      v[r] = x;
    }
    *(us4*)(drow + c4) = pack4(v[0], v[1], v[2], v[3]);
  }
#pragma unroll
  for (int c4 = 0; c4 < 16; c4 += 4)
    *(us4*)(drow + 64 + c4) = pack4(b1[(c4 + 0) * HW], b1[(c4 + 1) * HW],
                                    b1[(c4 + 2) * HW], b1[(c4 + 3) * HW]);
  const float* dn = dd + (size_t)n * 16 * HW + pp;
#pragma unroll
  for (int c4 = 0; c4 < 16; c4 += 4)
    *(us4*)(drow + 80 + c4) = pack4(dn[(c4 + 0) * HW], dn[(c4 + 1) * HW],
                                    dn[(c4 + 2) * HW], dn[(c4 + 3) * HW]);
  float s[4];
#pragma unroll
  for (int j = 0; j < 4; ++j) {
    const float f0 = b0[j * HW], f1 = b1[j * HW];
    const float sl0 = fminf(fmaxf(f0, 0.f), 1.f) * a + bb;
    const float sl1 = fminf(fmaxf(f1, 0.f), 1.f) * a + bb;
    const float om = 1.f - g[j];
    s[j] = om * om * sl0 + g[j] * g[j] * sl1;
    si_out[((size_t)n * 4 + j) * HW + pp] = s[j];
  }
  *(us4*)(drow + 96) = pack4(s[0], s[1], s[2], s[3]);
  const us4 zz = {0, 0, 0, 0};
#pragma unroll
  for (int c4 = 100; c4 < 128; c4 += 4) *(us4*)(drow + c4) = zz;
}

// Implicit-GEMM 3x3 conv, pad=1. Input NHWC bf16 (CIN = mult of 32).
// One block per output row (n,y). K-loop: per 32-ci chunk, stage rows y-1..y+1
// (258 x-slots, zero halo) into LDS ONCE via global_load_lds width=16, then run
// all 9 taps out of LDS. Weights loaded straight from global (L2-resident),
// software-pipelined one tap ahead.
// OMODE 0: bf16 NHWC out (64ch) + bias + relu
// OMODE 1: fp32 NCHW out (64ch) + bias            (denoise_out)
// OMODE 2: fp32 NCHW out (4ch)  + bias + sigmoid  (gamma, MT=1)
template <int CIN, int MT, int OMODE>
__global__ __launch_bounds__(256, 3) void conv3_k(
    const u16* __restrict__ in, const u16* __restrict__ wr,
    const float* __restrict__ bias, const u16* __restrict__ zrow,
    u16* __restrict__ obf, float* __restrict__ of32) {
  constexpr int M = MT * 16;
  constexpr int NCH = CIN / 32;
  // 12 regions: [row r (3)][k-group g (4)] x 258 pixel slots x 8 u16 (16B)
  __shared__ __align__(16) u16 Blds[12 * 258 * 8];
  const int tid = threadIdx.x;
  const int w = tid >> 6;
  const int lane = tid & 63;
  const int l15 = lane & 15;
  const int quad = lane >> 4;
  const int n = blockIdx.x >> 8;
  const int y = blockIdx.x & 255;

  f32x4 acc[MT][4];
#pragma unroll
  for (int mt = 0; mt < MT; ++mt)
#pragma unroll
    for (int nt = 0; nt < 4; ++nt) acc[mt][nt] = (f32x4){0.f, 0.f, 0.f, 0.f};

  const u16* inb = in + (size_t)n * HW * CIN;
  const u16* rp[3];
#pragma unroll
  for (int r = 0; r < 3; ++r) {
    const int y2 = y + r - 1;
    rp[r] = (y2 >= 0 && y2 < 256) ? (inb + (size_t)y2 * 256 * CIN) : zrow;
  }
  // zero the x-halo slots (0 and 257 of each region); never overwritten after
  if (tid < 24) {
    const int reg = tid >> 1;
    const int sl = (tid & 1) * 257;
    *(float4*)&Blds[(reg * 258 + sl) * 8] = (float4){0.f, 0.f, 0.f, 0.f};
  }

  for (int ch = 0; ch < NCH; ++ch) {
    const int ci0 = ch * 32;
    const int cg0 = ci0 >> 3;
    __syncthreads();   // prev chunk's compute done (and halo zeros visible)
    // stage B: 12 async 16B-per-lane copies; LDS dst = wave-uniform base + lane*16
#pragma unroll
    for (int r = 0; r < 3; ++r) {
      const u16* rowp = rp[r] + (size_t)tid * CIN + ci0;
#pragma unroll
      for (int g = 0; g < 4; ++g) {
        const u16* gp = rowp + g * 8;
        u16* lp = &Blds[(((r * 4 + g) * 258) + w * 64 + 1) * 8];
        __builtin_amdgcn_global_load_lds(
            (const __attribute__((address_space(1))) void*)gp,
            (__attribute__((address_space(3))) void*)lp, 16, 0, 0);
      }
    }
    __syncthreads();   // drains vmcnt -> staged data visible

    short8 a_cur[MT], a_nxt[MT];
#pragma unroll
    for (int mt = 0; mt < MT; ++mt)
      a_cur[mt] = *(const short8*)(wr +
          (size_t)((0 * (CIN / 8) + cg0 + quad) * M + mt * 16 + l15) * 8);
#pragma unroll
    for (int tap = 0; tap < 9; ++tap) {
      const int ky = tap / 3;
      const int kx = tap - ky * 3;
      if (tap < 8) {
#pragma unroll
        for (int mt = 0; mt < MT; ++mt)
          a_nxt[mt] = *(const short8*)(wr +
              (size_t)(((tap + 1) * (CIN / 8) + cg0 + quad) * M + mt * 16 + l15) * 8);
      }
      short8 b[4];
#pragma unroll
      for (int nt = 0; nt < 4; ++nt)
        b[nt] = *(const short8*)&Blds[((ky * 4 + quad) * 258 +
                                       (w * 4 + nt) * 16 + l15 + kx) * 8];
#pragma unroll
      for (int mt = 0; mt < MT; ++mt)
#pragma unroll
        for (int nt = 0; nt < 4; ++nt)
          acc[mt][nt] = __builtin_amdgcn_mfma_f32_16x16x32_bf16(a_cur[mt], b[nt], acc[mt][nt], 0, 0, 0);
      if (tap < 8) {
#pragma unroll
        for (int mt = 0; mt < MT; ++mt) a_cur[mt] = a_nxt[mt];
      }
    }
  }

  // Epilogue. C/D layout: col(pix)=lane&15, row(co within 16-tile)=quad*4+reg
  if (OMODE == 0) {
    u16* ob = obf + ((size_t)n * 256 + y) * 256 * 64;
#pragma unroll
    for (int mt = 0; mt < MT; ++mt) {
      const int co = mt * 16 + quad * 4;
      const float b0 = bias[co], b1 = bias[co + 1], b2 = bias[co + 2], b3 = bias[co + 3];
#pragma unroll
      for (int nt = 0; nt < 4; ++nt) {
        const int pix = (w * 4 + nt) * 16 + l15;
        f32x4 c = acc[mt][nt];
        us4 o = pack4(fmaxf(c[0] + b0, 0.f), fmaxf(c[1] + b1, 0.f),
                      fmaxf(c[2] + b2, 0.f), fmaxf(c[3] + b3, 0.f));
        *(us4*)(ob + (size_t)pix * 64 + co) = o;
      }
    }
  } else if (OMODE == 1) {
#pragma unroll
    for (int mt = 0; mt < MT; ++mt) {
#pragma unroll
      for (int nt = 0; nt < 4; ++nt) {
        const int pix = (w * 4 + nt) * 16 + l15;
        f32x4 c = acc[mt][nt];
#pragma unroll
        for (int r = 0; r < 4; ++r) {
          const int co = mt * 16 + quad * 4 + r;
          of32[((size_t)n * 64 + co) * HW + y * 256 + pix] = c[r] + bias[co];
        }
      }
    }
  } else {
    if (quad == 0) {
#pragma unroll
      for (int nt = 0; nt < 4; ++nt) {
        const int pix = (w * 4 + nt) * 16 + l15;
        f32x4 c = acc[0][nt];
#pragma unroll
        for (int r = 0; r < 4; ++r) {
          const float v = c[r] + bias[r];
          of32[((size_t)n * 4 + r) * HW + y * 256 + pix] = 1.f / (1.f + expf(-v));
        }
      }
    }
  }
}

extern "C" void kernel_launch(void* const* d_in, const int* in_sizes, int n_in,
                              void* d_out, int out_size, void* d_ws, size_t ws_size,
                              hipStream_t stream) {
  (void)in_sizes; (void)n_in; (void)out_size; (void)ws_size;
  const float* ft0 = (const float*)d_in[0];
  const float* ft1 = (const float*)d_in[1];
  const float* gup = (const float*)d_in[2];
  const float* dd  = (const float*)d_in[3];
  const float* ca  = (const float*)d_in[4];
  const float* cb  = (const float*)d_in[5];
  const float* fw1 = (const float*)d_in[6];  const float* fb1 = (const float*)d_in[7];
  const float* fw2 = (const float*)d_in[8];  const float* fb2 = (const float*)d_in[9];
  const float* fw3 = (const float*)d_in[10]; const float* fb3 = (const float*)d_in[11];
  const float* dw1 = (const float*)d_in[12]; const float* db1 = (const float*)d_in[13];
  const float* dw2 = (const float*)d_in[14]; const float* db2 = (const float*)d_in[15];
  const float* dw3 = (const float*)d_in[16]; const float* db3 = (const float*)d_in[17];

  float* out = (float*)d_out;
  float* fo_out = out;                               // fusion_out  4*64*HW
  float* do_out = out + (size_t)4 * 64 * HW;         // denoise_out 4*64*HW
  float* ga_out = out + (size_t)8 * 64 * HW;         // gamma       4*4*HW
  float* si_out = ga_out + (size_t)4 * 4 * HW;       // sigma       4*4*HW

  char* ws = (char*)d_ws;
  u16* WR1 = (u16*)(ws);                             // 9*4 *64*8  = 36864 B
  u16* WR2 = (u16*)(ws + 36864);                     // 9*8 *64*8  = 73728 B
  u16* WR3 = (u16*)(ws + 110592);                    // 9*8 *16*8  = 18432 B
  u16* WD1 = (u16*)(ws + 129024);                    // 9*16*64*8  = 147456 B
  u16* WD2 = (u16*)(ws + 276480);                    // 73728 B
  u16* WD3 = (u16*)(ws + 350208);                    // 73728 B
  u16* ZROW = (u16*)(ws + 425984);                   // 65536 B of zeros
  u16* FIN = (u16*)(ws + (1 << 20));                 // 4*HW*32  bf16 = 16 MB
  u16* H1  = (u16*)(ws + 17825792);                  // 4*HW*64  bf16 = 32 MB
  u16* H2  = (u16*)(ws + 51380224);                  // 4*HW*64  bf16 = 32 MB
  // denoise_in (4*HW*128 bf16 = 64 MB) overlaps denoise_out region: dead before dconv3 writes it
  u16* DIN = (u16*)do_out;

  hipMemsetAsync(ZROW, 0, 65536, stream);

  dim3 blk(256);
  reorder_w_k<<<(64 * 9 * 32 + 255) / 256, blk, 0, stream>>>(fw1, WR1, 64, 24, 64, 32);
  reorder_w_k<<<(64 * 9 * 64 + 255) / 256, blk, 0, stream>>>(fw2, WR2, 64, 64, 64, 64);
  reorder_w_k<<<(16 * 9 * 64 + 255) / 256, blk, 0, stream>>>(fw3, WR3, 4, 64, 16, 64);
  reorder_w_k<<<(64 * 9 * 128 + 255) / 256, blk, 0, stream>>>(dw1, WD1, 64, 100, 64, 128);
  reorder_w_k<<<(64 * 9 * 64 + 255) / 256, blk, 0, stream>>>(dw2, WD2, 64, 64, 64, 64);
  reorder_w_k<<<(64 * 9 * 64 + 255) / 256, blk, 0, stream>>>(dw3, WD3, 64, 64, 64, 64);

  fusion_in_k<<<1024, blk, 0, stream>>>(ft0, ft1, gup, ca, cb, FIN);
  conv3_k<32, 4, 0><<<1024, blk, 0, stream>>>(FIN, WR1, fb1, ZROW, H1, nullptr);
  conv3_k<64, 4, 0><<<1024, blk, 0, stream>>>(H1, WR2, fb2, ZROW, H2, nullptr);
  conv3_k<64, 1, 2><<<1024, blk, 0, stream>>>(H2, WR3, fb3, ZROW, nullptr, ga_out);
  fusion_post_k<<<1024, blk, 0, stream>>>(ft0, ft1, dd, ca, cb, ga_out, fo_out, si_out, DIN);
  conv3_k<128, 4, 0><<<1024, blk, 0, stream>>>(DIN, WD1, db1, ZROW, H1, nullptr);
  conv3_k<64, 4, 0><<<1024, blk, 0, stream>>>(H1, WD2, db2, ZROW, H2, nullptr);
  conv3_k<64, 4, 1><<<1024, blk, 0, stream>>>(H2, WD3, db3, ZROW, nullptr, do_out);
}

// Round 3
// 623.996 us; speedup vs baseline: 1.2411x; 1.1110x over previous
//
#include <hip/hip_runtime.h>
#include <stdint.h>

#define HW 65536

typedef __attribute__((ext_vector_type(8))) short short8;
typedef __attribute__((ext_vector_type(4))) float f32x4;
typedef unsigned short u16;

struct __align__(8) us4 { u16 x, y, z, w; };

__device__ __forceinline__ u16 f2bf(float f) {
  union { float f; uint32_t u; } v; v.f = f;
  uint32_t r = v.u + 0x7FFFu + ((v.u >> 16) & 1u);   // round-to-nearest-even
  return (u16)(r >> 16);
}

__device__ __forceinline__ us4 pack4(float a, float b, float c, float d) {
  us4 o; o.x = f2bf(a); o.y = f2bf(b); o.z = f2bf(c); o.w = f2bf(d); return o;
}

// Reorder OIHW fp32 weights -> bf16 [tap][cigroup][co][8], zero-padded in ci and co.
__global__ void reorder_w_k(const float* __restrict__ src, u16* __restrict__ dst,
                            int CO, int CI, int COp, int Cp) {
  int idx = blockIdx.x * 256 + threadIdx.x;
  int tot = COp * 9 * Cp;
  if (idx >= tot) return;
  int cc = idx & 7;
  int t = idx >> 3;
  int co = t % COp;
  int u = t / COp;
  int cgn = Cp >> 3;
  int cg = u % cgn;
  int tap = u / cgn;
  int ci = cg * 8 + cc;
  float v = 0.f;
  if (co < CO && ci < CI) v = src[(co * CI + ci) * 9 + tap];
  dst[idx] = f2bf(v);
}

// Build fusion_in: NHWC bf16, 32 ch (24 valid)
__global__ void fusion_in_k(const float* __restrict__ ft0, const float* __restrict__ ft1,
                            const float* __restrict__ gup, const float* __restrict__ ca,
                            const float* __restrict__ cb, u16* __restrict__ fin) {
  const int p = blockIdx.x * 256 + threadIdx.x;
  const int n = p >> 16;
  const int pp = p & 65535;
  const float* b0 = ft0 + (size_t)n * 64 * HW + pp;
  const float* b1 = ft1 + (size_t)n * 64 * HW + pp;
  const float a = ca[0], bb = cb[0];
  u16* row = fin + (size_t)p * 32;
#pragma unroll
  for (int c4 = 0; c4 < 16; c4 += 4)
    *(us4*)(row + c4) = pack4(fabsf(b1[(c4 + 0) * HW] - b0[(c4 + 0) * HW]),
                              fabsf(b1[(c4 + 1) * HW] - b0[(c4 + 1) * HW]),
                              fabsf(b1[(c4 + 2) * HW] - b0[(c4 + 2) * HW]),
                              fabsf(b1[(c4 + 3) * HW] - b0[(c4 + 3) * HW]));
  const float* gu = gup + (size_t)n * 4 * HW + pp;
  *(us4*)(row + 16) = pack4(gu[0], gu[HW], gu[2 * HW], gu[3 * HW]);
  *(us4*)(row + 20) = pack4(fminf(fmaxf(b1[0 * HW], 0.f), 1.f) * a + bb,
                            fminf(fmaxf(b1[1 * HW], 0.f), 1.f) * a + bb,
                            fminf(fmaxf(b1[2 * HW], 0.f), 1.f) * a + bb,
                            fminf(fmaxf(b1[3 * HW], 0.f), 1.f) * a + bb);
  const us4 zz = {0, 0, 0, 0};
  *(us4*)(row + 24) = zz;
  *(us4*)(row + 28) = zz;
}

// fusion_out (fp32 NCHW), sigma (fp32 NCHW), denoise_in NHWC bf16 128ch (100 valid)
__global__ void fusion_post_k(const float* __restrict__ ft0, const float* __restrict__ ft1,
                              const float* __restrict__ dd, const float* __restrict__ ca,
                              const float* __restrict__ cb, const float* __restrict__ gamma,
                              float* __restrict__ fo_out, float* __restrict__ si_out,
                              u16* __restrict__ din) {
  const int p = blockIdx.x * 256 + threadIdx.x;
  const int n = p >> 16;
  const int pp = p & 65535;
  const float* b0 = ft0 + (size_t)n * 64 * HW + pp;
  const float* b1 = ft1 + (size_t)n * 64 * HW + pp;
  float* fo = fo_out + (size_t)n * 64 * HW + pp;
  const float a = ca[0], bb = cb[0];
  float g[4];
#pragma unroll
  for (int j = 0; j < 4; ++j) g[j] = gamma[((size_t)n * 4 + j) * HW + pp];
  u16* drow = din + (size_t)p * 128;
#pragma unroll
  for (int c4 = 0; c4 < 64; c4 += 4) {
    const float gg = g[c4 >> 4];
    float v[4];
#pragma unroll
    for (int r = 0; r < 4; ++r) {
      const float f0 = b0[(c4 + r) * HW];
      const float f1 = b1[(c4 + r) * HW];
      const float x = f0 + gg * (f1 - f0);
      fo[(c4 + r) * HW] = x;
      v[r] = x;
    }
    *(us4*)(drow + c4) = pack4(v[0], v[1], v[2], v[3]);
  }
#pragma unroll
  for (int c4 = 0; c4 < 16; c4 += 4)
    *(us4*)(drow + 64 + c4) = pack4(b1[(c4 + 0) * HW], b1[(c4 + 1) * HW],
                                    b1[(c4 + 2) * HW], b1[(c4 + 3) * HW]);
  const float* dn = dd + (size_t)n * 16 * HW + pp;
#pragma unroll
  for (int c4 = 0; c4 < 16; c4 += 4)
    *(us4*)(drow + 80 + c4) = pack4(dn[(c4 + 0) * HW], dn[(c4 + 1) * HW],
                                    dn[(c4 + 2) * HW], dn[(c4 + 3) * HW]);
  float s[4];
#pragma unroll
  for (int j = 0; j < 4; ++j) {
    const float f0 = b0[j * HW], f1 = b1[j * HW];
    const float sl0 = fminf(fmaxf(f0, 0.f), 1.f) * a + bb;
    const float sl1 = fminf(fmaxf(f1, 0.f), 1.f) * a + bb;
    const float om = 1.f - g[j];
    s[j] = om * om * sl0 + g[j] * g[j] * sl1;
    si_out[((size_t)n * 4 + j) * HW + pp] = s[j];
  }
  *(us4*)(drow + 96) = pack4(s[0], s[1], s[2], s[3]);
  const us4 zz = {0, 0, 0, 0};
#pragma unroll
  for (int c4 = 100; c4 < 128; c4 += 4) *(us4*)(drow + c4) = zz;
}

// Implicit-GEMM 3x3 conv, pad=1, input NHWC bf16 (CIN mult of 32).
// Block = 2 output rows x 256 px, 512 threads (8 waves: yo=w>>2, quarter=w&3).
// Double-buffered LDS staging of 4 input rows x 32ci via global_load_lds(16B),
// overlapped with compute of the current chunk. Weights in registers: taps 0-4
// preloaded BEFORE issuing the next-chunk stage (vmcnt FIFO keeps stage loads
// outstanding), taps 5-8 via rolling 6-slot buffer.
// OMODE 0: bf16 NHWC out (64ch) + bias + relu
// OMODE 1: fp32 NCHW out (64ch) + bias            (denoise_out)
// OMODE 2: fp32 NCHW out (4ch)  + bias + sigmoid  (gamma, MT=1)
template <int CIN, int MT, int OMODE>
__global__ __launch_bounds__(512, 1) void conv3_k(
    const u16* __restrict__ in, const u16* __restrict__ wr,
    const float* __restrict__ bias, const u16* __restrict__ zrow,
    u16* __restrict__ obf, float* __restrict__ of32) {
  constexpr int M = MT * 16;
  constexpr int NCH = CIN / 32;
  constexpr int NREG = 16;      // 4 rows x 4 k-groups
  constexpr int RSTR = 259;     // 258 slots + 1 pad (bank offset 12, not 8)
  __shared__ __align__(16) u16 Blds[2 * NREG * RSTR * 8];   // 132.6 KB
  const int tid = threadIdx.x;
  const int w = tid >> 6;
  const int lane = tid & 63;
  const int l15 = lane & 15;
  const int quad = lane >> 4;
  const int yo = w >> 2;        // which of the 2 output rows
  const int wq = w & 3;         // 64-px quarter

  // XCD swizzle: consecutive y-tiles share an XCD for halo L2 reuse
  const int b = blockIdx.x;
  const int i = b >> 3;
  const int n = i >> 4;
  const int ytile = ((b & 7) << 4) + (i & 15);
  const int y0 = ytile * 2;

  f32x4 acc[MT][4];
#pragma unroll
  for (int mt = 0; mt < MT; ++mt)
#pragma unroll
    for (int nt = 0; nt < 4; ++nt) acc[mt][nt] = (f32x4){0.f, 0.f, 0.f, 0.f};

  const u16* inb = in + (size_t)n * HW * CIN;
  const u16* rp[4];
#pragma unroll
  for (int r = 0; r < 4; ++r) {
    const int y2 = y0 + r - 1;
    rp[r] = (y2 >= 0 && y2 < 256) ? (inb + (size_t)y2 * 256 * CIN) : zrow;
  }
  // zero x-halo slots (0 and 257) of all 32 regions (both buffers)
  if (tid < 64) {
    const int bf = tid >> 5;
    const int reg = (tid >> 1) & 15;
    const int sl = (tid & 1) * 257;
    *(float4*)&Blds[((bf * NREG + reg) * RSTR + sl) * 8] = (float4){0.f, 0.f, 0.f, 0.f};
  }

  auto stage = [&](int c, int bf) {
#pragma unroll
    for (int it = 0; it < 8; ++it) {
      const int reg = it * 2 + (tid >> 8);
      const int r = reg >> 2;
      const int g = reg & 3;
      const int slot = tid & 255;
      const u16* gp = rp[r] + (size_t)slot * CIN + c * 32 + g * 8;
      u16* lp = &Blds[((bf * NREG + reg) * RSTR + 1 + slot) * 8];
      __builtin_amdgcn_global_load_lds(
          (const __attribute__((address_space(1))) void*)gp,
          (__attribute__((address_space(3))) void*)lp, 16, 0, 0);
    }
  };

  stage(0, 0);

  for (int c = 0; c < NCH; ++c) {
    __syncthreads();   // drains stage(c); frees buffer (c+1)&1 from chunk c-1 reads
    const int cg0 = c * 4;
    const int bf = c & 1;
    short8 aw[6][MT];
    // taps 0-4 weights BEFORE stage issue -> their waits never drain the stage
#pragma unroll
    for (int t = 0; t < 5; ++t)
#pragma unroll
      for (int mt = 0; mt < MT; ++mt)
        aw[t][mt] = *(const short8*)(wr +
            (size_t)((t * (CIN / 8) + cg0 + quad) * M + mt * 16 + l15) * 8);
    if (c + 1 < NCH) stage(c + 1, bf ^ 1);
#pragma unroll
    for (int tap = 0; tap < 9; ++tap) {
      const int ky = tap / 3;
      const int kx = tap - ky * 3;
      if (tap < 4) {   // rolling prefetch of taps 5..8
        const int t2 = tap + 5;
        const int sl = t2 % 6;
#pragma unroll
        for (int mt = 0; mt < MT; ++mt)
          aw[sl][mt] = *(const short8*)(wr +
              (size_t)((t2 * (CIN / 8) + cg0 + quad) * M + mt * 16 + l15) * 8);
      }
      const int slcur = tap % 6;
      short8 bfrag[4];
#pragma unroll
      for (int nt = 0; nt < 4; ++nt)
        bfrag[nt] = *(const short8*)&Blds[((bf * NREG + (yo + ky) * 4 + quad) * RSTR +
                                           wq * 64 + nt * 16 + l15 + kx) * 8];
#pragma unroll
      for (int mt = 0; mt < MT; ++mt)
#pragma unroll
        for (int nt = 0; nt < 4; ++nt)
          acc[mt][nt] = __builtin_amdgcn_mfma_f32_16x16x32_bf16(aw[slcur][mt], bfrag[nt],
                                                                acc[mt][nt], 0, 0, 0);
    }
  }

  const int y = y0 + yo;
  // Epilogue. C/D: col(pix)=lane&15, row(co within tile)=quad*4+reg
  if (OMODE == 0) {
    u16* ob = obf + ((size_t)n * 256 + y) * 256 * 64;
#pragma unroll
    for (int mt = 0; mt < MT; ++mt) {
      const int co = mt * 16 + quad * 4;
      const float b0 = bias[co], b1 = bias[co + 1], b2 = bias[co + 2], b3 = bias[co + 3];
#pragma unroll
      for (int nt = 0; nt < 4; ++nt) {
        const int pix = (wq * 4 + nt) * 16 + l15;
        f32x4 cc = acc[mt][nt];
        us4 o = pack4(fmaxf(cc[0] + b0, 0.f), fmaxf(cc[1] + b1, 0.f),
                      fmaxf(cc[2] + b2, 0.f), fmaxf(cc[3] + b3, 0.f));
        *(us4*)(ob + (size_t)pix * 64 + co) = o;
      }
    }
  } else if (OMODE == 1) {
#pragma unroll
    for (int mt = 0; mt < MT; ++mt) {
#pragma unroll
      for (int nt = 0; nt < 4; ++nt) {
        const int pix = (wq * 4 + nt) * 16 + l15;
        f32x4 cc = acc[mt][nt];
#pragma unroll
        for (int r = 0; r < 4; ++r) {
          const int co = mt * 16 + quad * 4 + r;
          of32[((size_t)n * 64 + co) * HW + y * 256 + pix] = cc[r] + bias[co];
        }
      }
    }
  } else {
    if (quad == 0) {
#pragma unroll
      for (int nt = 0; nt < 4; ++nt) {
        const int pix = (wq * 4 + nt) * 16 + l15;
        f32x4 cc = acc[0][nt];
#pragma unroll
        for (int r = 0; r < 4; ++r) {
          const float v = cc[r] + bias[r];
          of32[((size_t)n * 4 + r) * HW + y * 256 + pix] = 1.f / (1.f + expf(-v));
        }
      }
    }
  }
}

extern "C" void kernel_launch(void* const* d_in, const int* in_sizes, int n_in,
                              void* d_out, int out_size, void* d_ws, size_t ws_size,
                              hipStream_t stream) {
  (void)in_sizes; (void)n_in; (void)out_size; (void)ws_size;
  const float* ft0 = (const float*)d_in[0];
  const float* ft1 = (const float*)d_in[1];
  const float* gup = (const float*)d_in[2];
  const float* dd  = (const float*)d_in[3];
  const float* ca  = (const float*)d_in[4];
  const float* cb  = (const float*)d_in[5];
  const float* fw1 = (const float*)d_in[6];  const float* fb1 = (const float*)d_in[7];
  const float* fw2 = (const float*)d_in[8];  const float* fb2 = (const float*)d_in[9];
  const float* fw3 = (const float*)d_in[10]; const float* fb3 = (const float*)d_in[11];
  const float* dw1 = (const float*)d_in[12]; const float* db1 = (const float*)d_in[13];
  const float* dw2 = (const float*)d_in[14]; const float* db2 = (const float*)d_in[15];
  const float* dw3 = (const float*)d_in[16]; const float* db3 = (const float*)d_in[17];

  float* out = (float*)d_out;
  float* fo_out = out;                               // fusion_out  4*64*HW
  float* do_out = out + (size_t)4 * 64 * HW;         // denoise_out 4*64*HW
  float* ga_out = out + (size_t)8 * 64 * HW;         // gamma       4*4*HW
  float* si_out = ga_out + (size_t)4 * 4 * HW;       // sigma       4*4*HW

  char* ws = (char*)d_ws;
  u16* WR1 = (u16*)(ws);
  u16* WR2 = (u16*)(ws + 36864);
  u16* WR3 = (u16*)(ws + 110592);
  u16* WD1 = (u16*)(ws + 129024);
  u16* WD2 = (u16*)(ws + 276480);
  u16* WD3 = (u16*)(ws + 350208);
  u16* ZROW = (u16*)(ws + 425984);                   // 64 KB zeros
  u16* FIN = (u16*)(ws + (1 << 20));                 // 16 MB
  u16* H1  = (u16*)(ws + 17825792);                  // 32 MB
  u16* H2  = (u16*)(ws + 51380224);                  // 32 MB
  u16* DIN = (u16*)do_out;                           // 64 MB, dead until dconv3

  hipMemsetAsync(ZROW, 0, 65536, stream);

  dim3 blk(256);
  reorder_w_k<<<(64 * 9 * 32 + 255) / 256, blk, 0, stream>>>(fw1, WR1, 64, 24, 64, 32);
  reorder_w_k<<<(64 * 9 * 64 + 255) / 256, blk, 0, stream>>>(fw2, WR2, 64, 64, 64, 64);
  reorder_w_k<<<(16 * 9 * 64 + 255) / 256, blk, 0, stream>>>(fw3, WR3, 4, 64, 16, 64);
  reorder_w_k<<<(64 * 9 * 128 + 255) / 256, blk, 0, stream>>>(dw1, WD1, 64, 100, 64, 128);
  reorder_w_k<<<(64 * 9 * 64 + 255) / 256, blk, 0, stream>>>(dw2, WD2, 64, 64, 64, 64);
  reorder_w_k<<<(64 * 9 * 64 + 255) / 256, blk, 0, stream>>>(dw3, WD3, 64, 64, 64, 64);

  dim3 cblk(512);
  fusion_in_k<<<1024, blk, 0, stream>>>(ft0, ft1, gup, ca, cb, FIN);
  conv3_k<32, 4, 0><<<512, cblk, 0, stream>>>(FIN, WR1, fb1, ZROW, H1, nullptr);
  conv3_k<64, 4, 0><<<512, cblk, 0, stream>>>(H1, WR2, fb2, ZROW, H2, nullptr);
  conv3_k<64, 1, 2><<<512, cblk, 0, stream>>>(H2, WR3, fb3, ZROW, nullptr, ga_out);
  fusion_post_k<<<1024, blk, 0, stream>>>(ft0, ft1, dd, ca, cb, ga_out, fo_out, si_out, DIN);
  conv3_k<128, 4, 0><<<512, cblk, 0, stream>>>(DIN, WD1, db1, ZROW, H1, nullptr);
  conv3_k<64, 4, 0><<<512, cblk, 0, stream>>>(H1, WD2, db2, ZROW, H2, nullptr);
  conv3_k<64, 4, 1><<<512, cblk, 0, stream>>>(H2, WD3, db3, ZROW, nullptr, do_out);
}